// Round 1
// baseline (770.914 us; speedup 1.0000x reference)
//
#include <hip/hip_runtime.h>
#include <math.h>

// ---------------------------------------------------------------------------
// REFT_Psi: B=65536 rows, DIM=64. 6 kernels:
//  kA  : mem-attn -> o_vec -> per-gate GRU input constants (batch-invariant)
//  kB1 : ctx = context@ctx_w^T (fp16 wts in LDS), prime softmax, theta_ideal,
//        res, omega, per-block stress partials (deterministic)
//  kB2 : emotion MLP -> e (written to out2 slot)
//  kS  : reduce 1024 stress partials (fp64)
//  kE  : out2 += 0.001*stress (in place)  -> e_theta
//  kC  : bi-GRU (blockIdx.y = dir), fp16 weights + mean-centering of e_theta
// Weight LDS strides are 8*odd halves => 16B-aligned b128 reads, uniform banks.
// ---------------------------------------------------------------------------

#define BATCH 65536
#define CTXD  384
#define NP    5
#define EPSV  1e-8f

typedef _Float16 h8 __attribute__((ext_vector_type(8)));

// output offsets (floats)
#define O0 0
#define O1 4194304
#define O2 12582912
#define O3 16777216
#define O4 16842752
#define O5 16908288

// workspace offsets (floats)
#define WS_STRESS 0
#define WS_PART   256
#define NPART     1024
#define WS_GICF   1536
#define WS_GICR   1792

__device__ __forceinline__ float wsum(float v) {
#pragma unroll
  for (int m = 1; m < 64; m <<= 1) v += __shfl_xor(v, m, 64);
  return v;
}

__device__ __forceinline__ float dot8(h8 w, float4 a, float4 b) {
  return (float)w[0]*a.x + (float)w[1]*a.y + (float)w[2]*a.z + (float)w[3]*a.w
       + (float)w[4]*b.x + (float)w[5]*b.y + (float)w[6]*b.z + (float)w[7]*b.w;
}

__device__ __forceinline__ float sigmoidf_(float x) {
  return 1.f / (1.f + __expf(-x));
}
__device__ __forceinline__ float tanhf_(float x) {
  // saturation-safe: x->+inf: e2=0 -> 1; x->-inf: e2=inf -> -1
  float e2 = __expf(-2.f * x);
  return 2.f / (1.f + e2) - 1.f;
}

// ---------------------------------------------------------------- kernel A
__global__ __launch_bounds__(256) void kA(
    const float* __restrict__ memory, const float* __restrict__ tw,
    const float* __restrict__ ipw, const float* __restrict__ ipb,
    const float* __restrict__ outw, const float* __restrict__ outb,
    const float* __restrict__ wihf, const float* __restrict__ bihf,
    const float* __restrict__ wihr, const float* __restrict__ bihr,
    float* __restrict__ ws)
{
  __shared__ float attn[16], mth[64], vv[64], ov[64];
  int t = threadIdx.x;
  if (t == 0) {
    float m = tw[0];
#pragma unroll
    for (int i = 1; i < 10; i++) m = fmaxf(m, tw[i]);
    float e[10]; float s = 0.f;
#pragma unroll
    for (int i = 0; i < 10; i++) { e[i] = __expf(tw[i] - m); s += e[i]; }
#pragma unroll
    for (int i = 0; i < 10; i++) attn[i] = e[i] / s;
  }
  __syncthreads();
  if (t < 64) {
    float a = 0.f;
#pragma unroll
    for (int m = 0; m < 10; m++) a += attn[m] * memory[m * 64 + t];
    mth[t] = a;
  }
  __syncthreads();
  if (t < 64) {
    float a = ipb[128 + t];
    for (int k = 0; k < 64; k++) a += mth[k] * ipw[(128 + t) * 64 + k];
    vv[t] = a;
  }
  __syncthreads();
  if (t < 64) {
    float a = outb[t];
    for (int k = 0; k < 64; k++) a += vv[k] * outw[t * 64 + k];
    ov[t] = a;
  }
  __syncthreads();
  if (t < 192) {
    float af = bihf[t], ar = bihr[t];
    for (int k = 0; k < 64; k++) {
      af += ov[k] * wihf[t * 130 + k];
      ar += ov[k] * wihr[t * 130 + k];
    }
    ws[WS_GICF + t] = af;
    ws[WS_GICR + t] = ar;
  }
}

// ---------------------------------------------------------------- kernel B1
__global__ __launch_bounds__(256) void kB1(
    const float* __restrict__ theta, const float* __restrict__ context,
    const float* __restrict__ ctxw, const float* __restrict__ ctxb,
    const float* __restrict__ idealw, const float* __restrict__ idealb,
    const float* __restrict__ pe, const float* __restrict__ pi,
    const float* __restrict__ fw, const float* __restrict__ fb,
    float* __restrict__ dout, float* __restrict__ ws)
{
  __shared__ __align__(16) _Float16 cw[64 * 392];   // stride 392 halves = 4*49 dw
  __shared__ __align__(16) float crow[4][CTXD];
  __shared__ float iw[NP * 128];
  __shared__ float pes[NP * 64];
  __shared__ float pis[64];
  __shared__ float sacc[4];
  int t = threadIdx.x, lane = t & 63, wv = t >> 6;

  for (int idx = t; idx < 64 * CTXD; idx += 256) {
    int j = idx / CTXD, k = idx - j * CTXD;
    cw[j * 392 + k] = (_Float16)ctxw[idx];
  }
  for (int idx = t; idx < NP * 128; idx += 256) iw[idx] = idealw[idx];
  for (int idx = t; idx < NP * 64; idx += 256) pes[idx] = pe[idx];
  if (t < 64) pis[t] = pi[t];
  float fwv = fw[0], fbv = fb[0];
  float ibv[NP];
#pragma unroll
  for (int l = 0; l < NP; l++) ibv[l] = idealb[l];
  float wacc = 0.f;
  __syncthreads();

  for (int i = 0; i < 16; i++) {
    int row = (blockIdx.x << 6) + (i << 2) + wv;
#pragma unroll
    for (int q = 0; q < 6; q++)
      crow[wv][lane + (q << 6)] = context[row * CTXD + lane + (q << 6)];
    __syncthreads();

    float th = theta[(row << 6) + lane];
    float acc = ctxb[lane];
    const _Float16* wr = &cw[lane * 392];
    const float4* xr = (const float4*)&crow[wv][0];
#pragma unroll 4
    for (int c = 0; c < 48; c++) {
      h8 w = *(const h8*)(wr + (c << 3));
      float4 xa = xr[c * 2], xb = xr[c * 2 + 1];
      acc += dot8(w, xa, xb);
    }
    float cx = acc;

    float L[NP];
#pragma unroll
    for (int l = 0; l < NP; l++) {
      float p = th * iw[l * 128 + lane] + cx * iw[l * 128 + 64 + lane];
      L[l] = wsum(p) + ibv[l];
    }
    float mx = L[0];
#pragma unroll
    for (int l = 1; l < NP; l++) mx = fmaxf(mx, L[l]);
    float P[NP], s = 0.f;
#pragma unroll
    for (int l = 0; l < NP; l++) { P[l] = __expf(L[l] - mx); s += P[l]; }
    float inv = 1.f / s;
#pragma unroll
    for (int l = 0; l < NP; l++) P[l] *= inv;
    if (lane < NP) {
      float v = P[0];
      if (lane == 1) v = P[1];
      else if (lane == 2) v = P[2];
      else if (lane == 3) v = P[3];
      else if (lane == 4) v = P[4];
      dout[O5 + row * NP + lane] = v;
    }

    float ti = 0.f;
#pragma unroll
    for (int l = 0; l < NP; l++) ti += P[l] * pes[l * 64 + lane];

    float a0 = th * th, a1 = ti * ti, a2 = th * ti;
    float dd = ti - pis[lane];
    float a3 = dd * dd;
#pragma unroll
    for (int m = 1; m < 64; m <<= 1) {
      a0 += __shfl_xor(a0, m, 64);
      a1 += __shfl_xor(a1, m, 64);
      a2 += __shfl_xor(a2, m, 64);
      a3 += __shfl_xor(a3, m, 64);
    }
    wacc += a0 - 2.f * a2 + a1;   // sum (th-ti)^2 for this row

    if (lane == 0) {
      float na = sqrtf(a0), nb = sqrtf(a1);
      float q = 1.f / ((na + EPSV) * (nb + EPSV));
      float num = a2 * q;
      float den = fmaxf(na * nb * q, EPSV);
      dout[O3 + row] = num / den;
      float fq = sqrtf(a3);
      float om = tanhf_(fq * fwv + fbv) * (1.f + 0.1f * __sinf(fq));
      dout[O4 + row] = om;
    }
    __syncthreads();
  }
  if (lane == 0) sacc[wv] = wacc;
  __syncthreads();
  if (t == 0) ws[WS_PART + blockIdx.x] = sacc[0] + sacc[1] + sacc[2] + sacc[3];
}

// ---------------------------------------------------------------- kernel B2
__global__ __launch_bounds__(256) void kB2(
    const float* __restrict__ theta,
    const float* __restrict__ w1, const float* __restrict__ b1,
    const float* __restrict__ w2, const float* __restrict__ b2,
    float* __restrict__ dout)
{
  __shared__ __align__(16) _Float16 w1h[128 * 72];   // 72 halves = 4*9 dw
  __shared__ __align__(16) _Float16 w2h[64 * 136];   // 136 halves = 4*17 dw
  __shared__ __align__(16) float trow[4][64];
  __shared__ __align__(16) float tmid[4][128];
  int t = threadIdx.x, lane = t & 63, wv = t >> 6;

  for (int idx = t; idx < 128 * 64; idx += 256) {
    int g = idx >> 6, k = idx & 63;
    w1h[g * 72 + k] = (_Float16)w1[idx];
  }
  for (int idx = t; idx < 64 * 128; idx += 256) {
    int g = idx >> 7, k = idx & 127;
    w2h[g * 136 + k] = (_Float16)w2[idx];
  }
  __syncthreads();

  for (int i = 0; i < 16; i++) {
    int row = (blockIdx.x << 6) + (i << 2) + wv;
    trow[wv][lane] = theta[(row << 6) + lane];
    __syncthreads();

    float acc0 = b1[lane], acc1 = b1[64 + lane];
    const _Float16* r0 = &w1h[lane * 72];
    const _Float16* r1 = &w1h[(lane + 64) * 72];
    const float4* xr = (const float4*)&trow[wv][0];
#pragma unroll
    for (int c = 0; c < 8; c++) {
      h8 wa = *(const h8*)(r0 + (c << 3));
      h8 wb = *(const h8*)(r1 + (c << 3));
      float4 xa = xr[c * 2], xb = xr[c * 2 + 1];
      acc0 += dot8(wa, xa, xb);
      acc1 += dot8(wb, xa, xb);
    }
    tmid[wv][lane]      = tanhf_(acc0);
    tmid[wv][64 + lane] = tanhf_(acc1);
    __syncthreads();

    float acc = b2[lane];
    const _Float16* r2 = &w2h[lane * 136];
    const float4* yr = (const float4*)&tmid[wv][0];
#pragma unroll 4
    for (int c = 0; c < 16; c++) {
      h8 w = *(const h8*)(r2 + (c << 3));
      float4 xa = yr[c * 2], xb = yr[c * 2 + 1];
      acc += dot8(w, xa, xb);
    }
    dout[O2 + (row << 6) + lane] = fmaxf(acc, 0.f);
    __syncthreads();
  }
}

// ---------------------------------------------------------------- kernel S
__global__ __launch_bounds__(256) void kS(float* __restrict__ ws)
{
  __shared__ double sd[256];
  int t = threadIdx.x;
  double a = 0.0;
  for (int i = t; i < NPART; i += 256) a += (double)ws[WS_PART + i];
  sd[t] = a;
  __syncthreads();
  for (int off = 128; off > 0; off >>= 1) {
    if (t < off) sd[t] += sd[t + off];
    __syncthreads();
  }
  if (t == 0) ws[WS_STRESS] = (float)sd[0];
}

// ---------------------------------------------------------------- kernel E
__global__ __launch_bounds__(256) void kE(float* __restrict__ dout,
                                          const float* __restrict__ ws)
{
  float sc = 0.001f * ws[WS_STRESS];
  int i = blockIdx.x * 256 + threadIdx.x;
  float4* p = (float4*)(dout + O2);
  float4 v = p[i];
  v.x += sc; v.y += sc; v.z += sc; v.w += sc;
  p[i] = v;
}

// ---------------------------------------------------------------- kernel C
__global__ __launch_bounds__(256) void kC(
    const float* __restrict__ theta, const float* __restrict__ hprev,
    const float* __restrict__ wihf, const float* __restrict__ whhf,
    const float* __restrict__ bhhf,
    const float* __restrict__ wihr, const float* __restrict__ whhr,
    const float* __restrict__ bhhr,
    const float* __restrict__ ws, float* __restrict__ dout)
{
  __shared__ __align__(16) _Float16 wiE[192 * 72];
  __shared__ __align__(16) _Float16 wH[192 * 72];
  __shared__ float wes[192], wre[192], wom[192], gic[192], bh[192];
  __shared__ __align__(16) float etc[4][64];
  __shared__ __align__(16) float hrw[4][64];
  int t = threadIdx.x, lane = t & 63, wv = t >> 6;
  int dir = blockIdx.y;
  const float* WIH = dir ? wihr : wihf;
  const float* WHH = dir ? whhr : whhf;
  const float* BHH = dir ? bhhr : bhhf;
  const float* GIC = ws + (dir ? WS_GICR : WS_GICF);

  for (int idx = t; idx < 192 * 64; idx += 256) {
    int g = idx >> 6, k = idx & 63;
    wiE[g * 72 + k] = (_Float16)WIH[g * 130 + 64 + k];
    wH[g * 72 + k]  = (_Float16)WHH[idx];
  }
  if (t < 192) {
    float s = 0.f;
    for (int k = 0; k < 64; k++) s += WIH[t * 130 + 64 + k];
    wes[t] = s;                      // exact fp32 row-sum for mean-centering
    wre[t] = WIH[t * 130 + 128];
    wom[t] = WIH[t * 130 + 129];
    gic[t] = GIC[t];
    bh[t]  = BHH[t];
  }
  __syncthreads();

  for (int i = 0; i < 32; i++) {
    int row = (blockIdx.x << 7) + (i << 2) + wv;
    float et = dout[O2 + (row << 6) + lane];          // e_theta
    float sr = wsum(et) * (1.f / 64.f);               // row mean (~5630)
    float hv = hprev[dir * (BATCH * 64) + (row << 6) + lane];
    etc[wv][lane] = et - sr;                          // exact (nearby floats)
    hrw[wv][lane] = hv;
    float rv = dout[O3 + row];
    float ov = dout[O4 + row];
    __syncthreads();

    float a0 = gic[lane]       + sr * wes[lane]       + rv * wre[lane]       + ov * wom[lane];
    float a1 = gic[64 + lane]  + sr * wes[64 + lane]  + rv * wre[64 + lane]  + ov * wom[64 + lane];
    float a2 = gic[128 + lane] + sr * wes[128 + lane] + rv * wre[128 + lane] + ov * wom[128 + lane];
    float h0 = bh[lane], h1 = bh[64 + lane], h2 = bh[128 + lane];
    const _Float16* p0 = &wiE[lane * 72];
    const _Float16* p1 = &wiE[(lane + 64) * 72];
    const _Float16* p2 = &wiE[(lane + 128) * 72];
    const _Float16* q0 = &wH[lane * 72];
    const _Float16* q1 = &wH[(lane + 64) * 72];
    const _Float16* q2 = &wH[(lane + 128) * 72];
    const float4* xe = (const float4*)&etc[wv][0];
    const float4* xh = (const float4*)&hrw[wv][0];
#pragma unroll 4
    for (int c = 0; c < 8; c++) {
      float4 ea = xe[c * 2], eb = xe[c * 2 + 1];
      float4 ha = xh[c * 2], hb = xh[c * 2 + 1];
      h8 w0 = *(const h8*)(p0 + (c << 3));
      h8 w1 = *(const h8*)(p1 + (c << 3));
      h8 w2 = *(const h8*)(p2 + (c << 3));
      h8 v0 = *(const h8*)(q0 + (c << 3));
      h8 v1 = *(const h8*)(q1 + (c << 3));
      h8 v2 = *(const h8*)(q2 + (c << 3));
      a0 += dot8(w0, ea, eb);
      a1 += dot8(w1, ea, eb);
      a2 += dot8(w2, ea, eb);
      h0 += dot8(v0, ha, hb);
      h1 += dot8(v1, ha, hb);
      h2 += dot8(v2, ha, hb);
    }
    float r = sigmoidf_(a0 + h0);
    float z = sigmoidf_(a1 + h1);
    float nn = tanhf_(a2 + r * h2);
    float hf = (1.f - z) * nn + z * hv;
    dout[O1 + dir * (BATCH * 64) + (row << 6) + lane] = hf;
    if (dir == 0) {
      float th = theta[(row << 6) + lane];
      dout[(row << 6) + lane] = 0.3f * th + 0.7f * hf;
    }
    __syncthreads();
  }
}

// ---------------------------------------------------------------- launch
extern "C" void kernel_launch(void* const* d_in, const int* in_sizes, int n_in,
                              void* d_out, int out_size, void* d_ws, size_t ws_size,
                              hipStream_t stream)
{
  const float* theta   = (const float*)d_in[0];
  const float* context = (const float*)d_in[1];
  const float* h_prev  = (const float*)d_in[2];
  const float* memory  = (const float*)d_in[3];
  const float* tw      = (const float*)d_in[4];
  const float* ipw     = (const float*)d_in[5];
  const float* ipb     = (const float*)d_in[6];
  const float* outw    = (const float*)d_in[7];
  const float* outb    = (const float*)d_in[8];
  const float* ew1     = (const float*)d_in[9];
  const float* eb1     = (const float*)d_in[10];
  const float* ew2     = (const float*)d_in[11];
  const float* eb2     = (const float*)d_in[12];
  const float* pe      = (const float*)d_in[13];
  const float* cw      = (const float*)d_in[14];
  const float* cb      = (const float*)d_in[15];
  const float* iw      = (const float*)d_in[16];
  const float* ib      = (const float*)d_in[17];
  const float* wihf    = (const float*)d_in[18];
  const float* whhf    = (const float*)d_in[19];
  const float* bihf    = (const float*)d_in[20];
  const float* bhhf    = (const float*)d_in[21];
  const float* wihr    = (const float*)d_in[22];
  const float* whhr    = (const float*)d_in[23];
  const float* bihr    = (const float*)d_in[24];
  const float* bhhr    = (const float*)d_in[25];
  const float* fw      = (const float*)d_in[26];
  const float* fb      = (const float*)d_in[27];
  const float* pi      = (const float*)d_in[28];
  float* dout = (float*)d_out;
  float* ws   = (float*)d_ws;

  kA<<<1, 256, 0, stream>>>(memory, tw, ipw, ipb, outw, outb, wihf, bihf, wihr, bihr, ws);
  kB1<<<1024, 256, 0, stream>>>(theta, context, cw, cb, iw, ib, pe, pi, fw, fb, dout, ws);
  kB2<<<1024, 256, 0, stream>>>(theta, ew1, eb1, ew2, eb2, dout);
  kS<<<1, 256, 0, stream>>>(ws);
  kE<<<4096, 256, 0, stream>>>(dout, ws);
  kC<<<dim3(512, 2, 1), 256, 0, stream>>>(theta, h_prev, wihf, whhf, bhhf,
                                          wihr, whhr, bhhr, ws, dout);
}

// Round 2
// 595.052 us; speedup vs baseline: 1.2955x; 1.2955x over previous
//
#include <hip/hip_runtime.h>
#include <math.h>

// ---------------------------------------------------------------------------
// REFT_Psi: B=65536 rows, DIM=64. 6 kernels:
//  kA  : mem-attn -> o_vec -> per-gate GRU input constants (batch-invariant)
//  kB1 : ctx = context@ctx_w^T (fp16 wts in LDS), prime softmax, theta_ideal,
//        res, omega, per-block stress partials (deterministic)
//  kB2 : emotion MLP -> e (written to out2 slot)
//  kS  : reduce 1024 stress partials (fp64)
//  kE  : out2 += 0.001*stress (in place)  -> e_theta
//  kC  : bi-GRU via MFMA 16x16x32_f16. Per dir: gates = [e_c|h] @ W^T,
//        K=128, N=256 (r | z | i_n | h_n). fp16 weights/inputs, fp32 acc.
//        Large-mean e_theta handled by mean-centering; rank-1 terms
//        (sr*rowsum, res, omega) stay fp32 in the epilogue.
//        C-layout (col=lane&15,row=quad*4+reg) => all 4 gates of a (row,dim)
//        land in the same lane; wave computes all 16 N-tiles of its 16 rows.
// ---------------------------------------------------------------------------

#define BATCH 65536
#define CTXD  384
#define NP    5
#define EPSV  1e-8f

typedef _Float16 h8 __attribute__((ext_vector_type(8)));
typedef float f32x4 __attribute__((ext_vector_type(4)));

// output offsets (floats)
#define O0 0
#define O1 4194304
#define O2 12582912
#define O3 16777216
#define O4 16842752
#define O5 16908288

// workspace offsets (floats)
#define WS_STRESS 0
#define WS_PART   256
#define NPART     1024
#define WS_GICF   1536
#define WS_GICR   1792

__device__ __forceinline__ float wsum(float v) {
#pragma unroll
  for (int m = 1; m < 64; m <<= 1) v += __shfl_xor(v, m, 64);
  return v;
}

__device__ __forceinline__ float dot8(h8 w, float4 a, float4 b) {
  return (float)w[0]*a.x + (float)w[1]*a.y + (float)w[2]*a.z + (float)w[3]*a.w
       + (float)w[4]*b.x + (float)w[5]*b.y + (float)w[6]*b.z + (float)w[7]*b.w;
}

__device__ __forceinline__ float sigmoidf_(float x) {
  return 1.f / (1.f + __expf(-x));
}
__device__ __forceinline__ float tanhf_(float x) {
  float e2 = __expf(-2.f * x);
  return 2.f / (1.f + e2) - 1.f;
}

// ---------------------------------------------------------------- kernel A
__global__ __launch_bounds__(256) void kA(
    const float* __restrict__ memory, const float* __restrict__ tw,
    const float* __restrict__ ipw, const float* __restrict__ ipb,
    const float* __restrict__ outw, const float* __restrict__ outb,
    const float* __restrict__ wihf, const float* __restrict__ bihf,
    const float* __restrict__ wihr, const float* __restrict__ bihr,
    float* __restrict__ ws)
{
  __shared__ float attn[16], mth[64], vv[64], ov[64];
  int t = threadIdx.x;
  if (t == 0) {
    float m = tw[0];
#pragma unroll
    for (int i = 1; i < 10; i++) m = fmaxf(m, tw[i]);
    float e[10]; float s = 0.f;
#pragma unroll
    for (int i = 0; i < 10; i++) { e[i] = __expf(tw[i] - m); s += e[i]; }
#pragma unroll
    for (int i = 0; i < 10; i++) attn[i] = e[i] / s;
  }
  __syncthreads();
  if (t < 64) {
    float a = 0.f;
#pragma unroll
    for (int m = 0; m < 10; m++) a += attn[m] * memory[m * 64 + t];
    mth[t] = a;
  }
  __syncthreads();
  if (t < 64) {
    float a = ipb[128 + t];
    for (int k = 0; k < 64; k++) a += mth[k] * ipw[(128 + t) * 64 + k];
    vv[t] = a;
  }
  __syncthreads();
  if (t < 64) {
    float a = outb[t];
    for (int k = 0; k < 64; k++) a += vv[k] * outw[t * 64 + k];
    ov[t] = a;
  }
  __syncthreads();
  if (t < 192) {
    float af = bihf[t], ar = bihr[t];
    for (int k = 0; k < 64; k++) {
      af += ov[k] * wihf[t * 130 + k];
      ar += ov[k] * wihr[t * 130 + k];
    }
    ws[WS_GICF + t] = af;
    ws[WS_GICR + t] = ar;
  }
}

// ---------------------------------------------------------------- kernel B1
__global__ __launch_bounds__(256) void kB1(
    const float* __restrict__ theta, const float* __restrict__ context,
    const float* __restrict__ ctxw, const float* __restrict__ ctxb,
    const float* __restrict__ idealw, const float* __restrict__ idealb,
    const float* __restrict__ pe, const float* __restrict__ pi,
    const float* __restrict__ fw, const float* __restrict__ fb,
    float* __restrict__ dout, float* __restrict__ ws)
{
  __shared__ __align__(16) _Float16 cw[64 * 392];   // stride 392 halves = 4*49 dw
  __shared__ __align__(16) float crow[4][CTXD];
  __shared__ float iw[NP * 128];
  __shared__ float pes[NP * 64];
  __shared__ float pis[64];
  __shared__ float sacc[4];
  int t = threadIdx.x, lane = t & 63, wv = t >> 6;

  for (int idx = t; idx < 64 * CTXD; idx += 256) {
    int j = idx / CTXD, k = idx - j * CTXD;
    cw[j * 392 + k] = (_Float16)ctxw[idx];
  }
  for (int idx = t; idx < NP * 128; idx += 256) iw[idx] = idealw[idx];
  for (int idx = t; idx < NP * 64; idx += 256) pes[idx] = pe[idx];
  if (t < 64) pis[t] = pi[t];
  float fwv = fw[0], fbv = fb[0];
  float ibv[NP];
#pragma unroll
  for (int l = 0; l < NP; l++) ibv[l] = idealb[l];
  float wacc = 0.f;
  __syncthreads();

  for (int i = 0; i < 16; i++) {
    int row = (blockIdx.x << 6) + (i << 2) + wv;
#pragma unroll
    for (int q = 0; q < 6; q++)
      crow[wv][lane + (q << 6)] = context[row * CTXD + lane + (q << 6)];
    __syncthreads();

    float th = theta[(row << 6) + lane];
    float acc = ctxb[lane];
    const _Float16* wr = &cw[lane * 392];
    const float4* xr = (const float4*)&crow[wv][0];
#pragma unroll 4
    for (int c = 0; c < 48; c++) {
      h8 w = *(const h8*)(wr + (c << 3));
      float4 xa = xr[c * 2], xb = xr[c * 2 + 1];
      acc += dot8(w, xa, xb);
    }
    float cx = acc;

    float L[NP];
#pragma unroll
    for (int l = 0; l < NP; l++) {
      float p = th * iw[l * 128 + lane] + cx * iw[l * 128 + 64 + lane];
      L[l] = wsum(p) + ibv[l];
    }
    float mx = L[0];
#pragma unroll
    for (int l = 1; l < NP; l++) mx = fmaxf(mx, L[l]);
    float P[NP], s = 0.f;
#pragma unroll
    for (int l = 0; l < NP; l++) { P[l] = __expf(L[l] - mx); s += P[l]; }
    float inv = 1.f / s;
#pragma unroll
    for (int l = 0; l < NP; l++) P[l] *= inv;
    if (lane < NP) {
      float v = P[0];
      if (lane == 1) v = P[1];
      else if (lane == 2) v = P[2];
      else if (lane == 3) v = P[3];
      else if (lane == 4) v = P[4];
      dout[O5 + row * NP + lane] = v;
    }

    float ti = 0.f;
#pragma unroll
    for (int l = 0; l < NP; l++) ti += P[l] * pes[l * 64 + lane];

    float a0 = th * th, a1 = ti * ti, a2 = th * ti;
    float dd = ti - pis[lane];
    float a3 = dd * dd;
#pragma unroll
    for (int m = 1; m < 64; m <<= 1) {
      a0 += __shfl_xor(a0, m, 64);
      a1 += __shfl_xor(a1, m, 64);
      a2 += __shfl_xor(a2, m, 64);
      a3 += __shfl_xor(a3, m, 64);
    }
    wacc += a0 - 2.f * a2 + a1;   // sum (th-ti)^2 for this row

    if (lane == 0) {
      float na = sqrtf(a0), nb = sqrtf(a1);
      float q = 1.f / ((na + EPSV) * (nb + EPSV));
      float num = a2 * q;
      float den = fmaxf(na * nb * q, EPSV);
      dout[O3 + row] = num / den;
      float fq = sqrtf(a3);
      float om = tanhf_(fq * fwv + fbv) * (1.f + 0.1f * __sinf(fq));
      dout[O4 + row] = om;
    }
    __syncthreads();
  }
  if (lane == 0) sacc[wv] = wacc;
  __syncthreads();
  if (t == 0) ws[WS_PART + blockIdx.x] = sacc[0] + sacc[1] + sacc[2] + sacc[3];
}

// ---------------------------------------------------------------- kernel B2
__global__ __launch_bounds__(256) void kB2(
    const float* __restrict__ theta,
    const float* __restrict__ w1, const float* __restrict__ b1,
    const float* __restrict__ w2, const float* __restrict__ b2,
    float* __restrict__ dout)
{
  __shared__ __align__(16) _Float16 w1h[128 * 72];   // 72 halves = 4*9 dw
  __shared__ __align__(16) _Float16 w2h[64 * 136];   // 136 halves = 4*17 dw
  __shared__ __align__(16) float trow[4][64];
  __shared__ __align__(16) float tmid[4][128];
  int t = threadIdx.x, lane = t & 63, wv = t >> 6;

  for (int idx = t; idx < 128 * 64; idx += 256) {
    int g = idx >> 6, k = idx & 63;
    w1h[g * 72 + k] = (_Float16)w1[idx];
  }
  for (int idx = t; idx < 64 * 128; idx += 256) {
    int g = idx >> 7, k = idx & 127;
    w2h[g * 136 + k] = (_Float16)w2[idx];
  }
  __syncthreads();

  for (int i = 0; i < 16; i++) {
    int row = (blockIdx.x << 6) + (i << 2) + wv;
    trow[wv][lane] = theta[(row << 6) + lane];
    __syncthreads();

    float acc0 = b1[lane], acc1 = b1[64 + lane];
    const _Float16* r0 = &w1h[lane * 72];
    const _Float16* r1 = &w1h[(lane + 64) * 72];
    const float4* xr = (const float4*)&trow[wv][0];
#pragma unroll
    for (int c = 0; c < 8; c++) {
      h8 wa = *(const h8*)(r0 + (c << 3));
      h8 wb = *(const h8*)(r1 + (c << 3));
      float4 xa = xr[c * 2], xb = xr[c * 2 + 1];
      acc0 += dot8(wa, xa, xb);
      acc1 += dot8(wb, xa, xb);
    }
    tmid[wv][lane]      = tanhf_(acc0);
    tmid[wv][64 + lane] = tanhf_(acc1);
    __syncthreads();

    float acc = b2[lane];
    const _Float16* r2 = &w2h[lane * 136];
    const float4* yr = (const float4*)&tmid[wv][0];
#pragma unroll 4
    for (int c = 0; c < 16; c++) {
      h8 w = *(const h8*)(r2 + (c << 3));
      float4 xa = yr[c * 2], xb = yr[c * 2 + 1];
      acc += dot8(w, xa, xb);
    }
    dout[O2 + (row << 6) + lane] = fmaxf(acc, 0.f);
    __syncthreads();
  }
}

// ---------------------------------------------------------------- kernel S
__global__ __launch_bounds__(256) void kS(float* __restrict__ ws)
{
  __shared__ double sd[256];
  int t = threadIdx.x;
  double a = 0.0;
  for (int i = t; i < NPART; i += 256) a += (double)ws[WS_PART + i];
  sd[t] = a;
  __syncthreads();
  for (int off = 128; off > 0; off >>= 1) {
    if (t < off) sd[t] += sd[t + off];
    __syncthreads();
  }
  if (t == 0) ws[WS_STRESS] = (float)sd[0];
}

// ---------------------------------------------------------------- kernel E
__global__ __launch_bounds__(256) void kE(float* __restrict__ dout,
                                          const float* __restrict__ ws)
{
  float sc = 0.001f * ws[WS_STRESS];
  int i = blockIdx.x * 256 + threadIdx.x;
  float4* p = (float4*)(dout + O2);
  float4 v = p[i];
  v.x += sc; v.y += sc; v.z += sc; v.w += sc;
  p[i] = v;
}

// ---------------------------------------------------------------- kernel C
// MFMA bi-GRU. grid (256, 2): bx covers 256 rows (4 M-blocks of 64), by=dir.
// LDS 74.8 KB => 2 blocks/CU.
__global__ __launch_bounds__(256) void kC(
    const float* __restrict__ theta, const float* __restrict__ hprev,
    const float* __restrict__ wihf, const float* __restrict__ whhf,
    const float* __restrict__ bhhf,
    const float* __restrict__ wihr, const float* __restrict__ whhr,
    const float* __restrict__ bhhr,
    const float* __restrict__ ws, float* __restrict__ dout)
{
  // weights, fp16, stored [n][k] (B^T) with padded strides for b128 reads
  __shared__ __align__(16) _Float16 WRZ[128 * 136];  // r,z gates: k=[e_c(64)|h(64)]
  __shared__ __align__(16) _Float16 WN [64 * 72];    // i_n gate: k=e_c only
  __shared__ __align__(16) _Float16 WHN[64 * 72];    // h_n gate: k=h only
  __shared__ __align__(16) _Float16 ABuf[64 * 136];  // [row][e_c(64)|h(64)] fp16
  __shared__ float cg[192], wes[192], wre[192], wom[192], bhn[64];
  __shared__ float sLDS[64], rLDS[64], oLDS[64];

  int t = threadIdx.x, lane = t & 63, wv = t >> 6;
  int q = lane >> 4, col = lane & 15;
  int dir = blockIdx.y;
  const float* WIH = dir ? wihr : wihf;
  const float* WHH = dir ? whhr : whhf;
  const float* BHH = dir ? bhhr : bhhf;
  const float* GIC = ws + (dir ? WS_GICR : WS_GICF);

  // ---- stage weights (once per block) ----
  for (int idx = t; idx < 128 * 128; idx += 256) {
    int n = idx >> 7, k = idx & 127;
    float v = (k < 64) ? WIH[n * 130 + 64 + k] : WHH[n * 64 + (k - 64)];
    WRZ[n * 136 + k] = (_Float16)v;
  }
  for (int idx = t; idx < 64 * 64; idx += 256) {
    int n = idx >> 6, k = idx & 63;
    WN [n * 72 + k] = (_Float16)WIH[(128 + n) * 130 + 64 + k];
    WHN[n * 72 + k] = (_Float16)WHH[(128 + n) * 64 + k];
  }
  if (t < 192) {
    float s = 0.f;
    for (int k = 0; k < 64; k++) s += WIH[t * 130 + 64 + k];
    wes[t] = s;                      // exact fp32 row-sum for mean-centering
    wre[t] = WIH[t * 130 + 128];
    wom[t] = WIH[t * 130 + 129];
    cg[t]  = GIC[t] + (t < 128 ? BHH[t] : 0.f);  // fold bhh into r,z gates
  }
  if (t < 64) bhn[t] = BHH[128 + t];
  __syncthreads();

  for (int m = 0; m < 4; m++) {
    int Mbase = (blockIdx.x << 8) + (m << 6);

    // ---- stage A: 64 rows, wave wv handles rows 4i+wv ----
    for (int i = 0; i < 16; i++) {
      int lr = (i << 2) + wv;
      int row = Mbase + lr;
      float ev = dout[O2 + (row << 6) + lane];                 // e_theta ~5630
      float hv = hprev[dir * (BATCH * 64) + (row << 6) + lane];
      float sr = wsum(ev) * 0.015625f;                          // row mean
      ABuf[lr * 136 + lane]      = (_Float16)(ev - sr);         // centered, O(1)
      ABuf[lr * 136 + 64 + lane] = (_Float16)hv;
      if (lane == 0) sLDS[lr] = sr;
    }
    if (t < 64) {
      rLDS[t] = dout[O3 + Mbase + t];
      oLDS[t] = dout[O4 + Mbase + t];
    }
    __syncthreads();

    // ---- MFMA: wave wv owns rows [16wv,16wv+16), all 256 gate outputs ----
    const _Float16* arow = &ABuf[(16 * wv + col) * 136 + q * 8];
    h8 a0 = *(const h8*)(arow);        // k  0..31  (e_c)
    h8 a1 = *(const h8*)(arow + 32);   // k 32..63  (e_c)
    h8 a2 = *(const h8*)(arow + 64);   // k 64..95  (h)
    h8 a3 = *(const h8*)(arow + 96);   // k 96..127 (h)

    f32x4 accR[4], accZ[4], accN[4], accH[4];
#pragma unroll
    for (int td = 0; td < 4; td++) {
      accR[td] = (f32x4)(0.f); accZ[td] = (f32x4)(0.f);
      accN[td] = (f32x4)(0.f); accH[td] = (f32x4)(0.f);
    }
#pragma unroll
    for (int td = 0; td < 4; td++) {
      const _Float16* br = &WRZ[(td * 16 + col) * 136 + q * 8];
      accR[td] = __builtin_amdgcn_mfma_f32_16x16x32_f16(a0, *(const h8*)(br),      accR[td], 0, 0, 0);
      accR[td] = __builtin_amdgcn_mfma_f32_16x16x32_f16(a1, *(const h8*)(br + 32), accR[td], 0, 0, 0);
      accR[td] = __builtin_amdgcn_mfma_f32_16x16x32_f16(a2, *(const h8*)(br + 64), accR[td], 0, 0, 0);
      accR[td] = __builtin_amdgcn_mfma_f32_16x16x32_f16(a3, *(const h8*)(br + 96), accR[td], 0, 0, 0);
      const _Float16* bz = &WRZ[(64 + td * 16 + col) * 136 + q * 8];
      accZ[td] = __builtin_amdgcn_mfma_f32_16x16x32_f16(a0, *(const h8*)(bz),      accZ[td], 0, 0, 0);
      accZ[td] = __builtin_amdgcn_mfma_f32_16x16x32_f16(a1, *(const h8*)(bz + 32), accZ[td], 0, 0, 0);
      accZ[td] = __builtin_amdgcn_mfma_f32_16x16x32_f16(a2, *(const h8*)(bz + 64), accZ[td], 0, 0, 0);
      accZ[td] = __builtin_amdgcn_mfma_f32_16x16x32_f16(a3, *(const h8*)(bz + 96), accZ[td], 0, 0, 0);
      const _Float16* bn = &WN[(td * 16 + col) * 72 + q * 8];
      accN[td] = __builtin_amdgcn_mfma_f32_16x16x32_f16(a0, *(const h8*)(bn),      accN[td], 0, 0, 0);
      accN[td] = __builtin_amdgcn_mfma_f32_16x16x32_f16(a1, *(const h8*)(bn + 32), accN[td], 0, 0, 0);
      const _Float16* bh = &WHN[(td * 16 + col) * 72 + q * 8];
      accH[td] = __builtin_amdgcn_mfma_f32_16x16x32_f16(a2, *(const h8*)(bh),      accH[td], 0, 0, 0);
      accH[td] = __builtin_amdgcn_mfma_f32_16x16x32_f16(a3, *(const h8*)(bh + 32), accH[td], 0, 0, 0);
    }

    // ---- epilogue: C-layout col=lane&15, row=q*4+reg ----
#pragma unroll
    for (int reg = 0; reg < 4; reg++) {
      int lr  = 16 * wv + q * 4 + reg;
      int row = Mbase + lr;
      float sr = sLDS[lr], rv = rLDS[lr], ov = oLDS[lr];
#pragma unroll
      for (int td = 0; td < 4; td++) {
        int d = td * 16 + col;
        float hv = (float)ABuf[lr * 136 + 64 + d];
        float A0 = accR[td][reg] + cg[d]       + sr * wes[d]       + rv * wre[d]       + ov * wom[d];
        float A1 = accZ[td][reg] + cg[64 + d]  + sr * wes[64 + d]  + rv * wre[64 + d]  + ov * wom[64 + d];
        float AN = accN[td][reg] + cg[128 + d] + sr * wes[128 + d] + rv * wre[128 + d] + ov * wom[128 + d];
        float AH = accH[td][reg] + bhn[d];
        float r  = sigmoidf_(A0);
        float z  = sigmoidf_(A1);
        float nn = tanhf_(AN + r * AH);
        float hf = (1.f - z) * nn + z * hv;
        dout[O1 + dir * (BATCH * 64) + (row << 6) + d] = hf;
        if (dir == 0) {
          dout[(row << 6) + d] = 0.3f * theta[(row << 6) + d] + 0.7f * hf;
        }
      }
    }
    __syncthreads();   // before restaging ABuf
  }
}

// ---------------------------------------------------------------- launch
extern "C" void kernel_launch(void* const* d_in, const int* in_sizes, int n_in,
                              void* d_out, int out_size, void* d_ws, size_t ws_size,
                              hipStream_t stream)
{
  const float* theta   = (const float*)d_in[0];
  const float* context = (const float*)d_in[1];
  const float* h_prev  = (const float*)d_in[2];
  const float* memory  = (const float*)d_in[3];
  const float* tw      = (const float*)d_in[4];
  const float* ipw     = (const float*)d_in[5];
  const float* ipb     = (const float*)d_in[6];
  const float* outw    = (const float*)d_in[7];
  const float* outb    = (const float*)d_in[8];
  const float* ew1     = (const float*)d_in[9];
  const float* eb1     = (const float*)d_in[10];
  const float* ew2     = (const float*)d_in[11];
  const float* eb2     = (const float*)d_in[12];
  const float* pe      = (const float*)d_in[13];
  const float* cw      = (const float*)d_in[14];
  const float* cb      = (const float*)d_in[15];
  const float* iw      = (const float*)d_in[16];
  const float* ib      = (const float*)d_in[17];
  const float* wihf    = (const float*)d_in[18];
  const float* whhf    = (const float*)d_in[19];
  const float* bihf    = (const float*)d_in[20];
  const float* bhhf    = (const float*)d_in[21];
  const float* wihr    = (const float*)d_in[22];
  const float* whhr    = (const float*)d_in[23];
  const float* bihr    = (const float*)d_in[24];
  const float* bhhr    = (const float*)d_in[25];
  const float* fw      = (const float*)d_in[26];
  const float* fb      = (const float*)d_in[27];
  const float* pi      = (const float*)d_in[28];
  float* dout = (float*)d_out;
  float* ws   = (float*)d_ws;

  kA<<<1, 256, 0, stream>>>(memory, tw, ipw, ipb, outw, outb, wihf, bihf, wihr, bihr, ws);
  kB1<<<1024, 256, 0, stream>>>(theta, context, cw, cb, iw, ib, pe, pi, fw, fb, dout, ws);
  kB2<<<1024, 256, 0, stream>>>(theta, ew1, eb1, ew2, eb2, dout);
  kS<<<1, 256, 0, stream>>>(ws);
  kE<<<4096, 256, 0, stream>>>(dout, ws);
  kC<<<dim3(256, 2, 1), 256, 0, stream>>>(theta, h_prev, wihf, whhf, bhhf,
                                          wihr, whhr, bhhr, ws, dout);
}

// Round 3
// 437.751 us; speedup vs baseline: 1.7611x; 1.3593x over previous
//
#include <hip/hip_runtime.h>
#include <math.h>

// ---------------------------------------------------------------------------
// REFT_Psi: B=65536 rows, DIM=64. 6 kernels:
//  kA  : mem-attn -> o_vec -> per-gate GRU input constants (batch-invariant)
//  kB1 : MFMA ctx GEMM (context[64x384] @ ctx_w^T, fp16 frags) + per-row
//        epilogue: prime softmax, theta_ideal, res, omega, stress partials
//  kB2 : MFMA emotion MLP 64->128->64 (fp16 frags) -> e in out2 slot
//  kS  : reduce 1024 stress partials (fp64)
//  kE  : out2 += 0.001*stress (in place)  -> e_theta
//  kC  : bi-GRU via MFMA 16x16x32_f16 (mean-centered e_theta, fp32 rank-1
//        terms in epilogue)
// Fragment convention (verified in kC round 2): A[m=lane&15][k=(lane>>4)*8+j],
// B[n=lane&15][k=...], C col=lane&15, row=(lane>>4)*4+reg.
// ---------------------------------------------------------------------------

#define BATCH 65536
#define CTXD  384
#define NP    5
#define EPSV  1e-8f

typedef _Float16 h8 __attribute__((ext_vector_type(8)));
typedef _Float16 h4 __attribute__((ext_vector_type(4)));
typedef float f32x4 __attribute__((ext_vector_type(4)));

// output offsets (floats)
#define O0 0
#define O1 4194304
#define O2 12582912
#define O3 16777216
#define O4 16842752
#define O5 16908288

// workspace offsets (floats)
#define WS_STRESS 0
#define WS_PART   256
#define NPART     1024
#define WS_GICF   1536
#define WS_GICR   1792

__device__ __forceinline__ float wsum(float v) {
#pragma unroll
  for (int m = 1; m < 64; m <<= 1) v += __shfl_xor(v, m, 64);
  return v;
}

__device__ __forceinline__ float sigmoidf_(float x) {
  return 1.f / (1.f + __expf(-x));
}
__device__ __forceinline__ float tanhf_(float x) {
  float e2 = __expf(-2.f * x);
  return 2.f / (1.f + e2) - 1.f;
}

__device__ __forceinline__ h4 cvt4(float4 v) {
  h4 o = {(_Float16)v.x, (_Float16)v.y, (_Float16)v.z, (_Float16)v.w};
  return o;
}

// ---------------------------------------------------------------- kernel A
__global__ __launch_bounds__(256) void kA(
    const float* __restrict__ memory, const float* __restrict__ tw,
    const float* __restrict__ ipw, const float* __restrict__ ipb,
    const float* __restrict__ outw, const float* __restrict__ outb,
    const float* __restrict__ wihf, const float* __restrict__ bihf,
    const float* __restrict__ wihr, const float* __restrict__ bihr,
    float* __restrict__ ws)
{
  __shared__ float attn[16], mth[64], vv[64], ov[64];
  int t = threadIdx.x;
  if (t == 0) {
    float m = tw[0];
#pragma unroll
    for (int i = 1; i < 10; i++) m = fmaxf(m, tw[i]);
    float e[10]; float s = 0.f;
#pragma unroll
    for (int i = 0; i < 10; i++) { e[i] = __expf(tw[i] - m); s += e[i]; }
#pragma unroll
    for (int i = 0; i < 10; i++) attn[i] = e[i] / s;
  }
  __syncthreads();
  if (t < 64) {
    float a = 0.f;
#pragma unroll
    for (int m = 0; m < 10; m++) a += attn[m] * memory[m * 64 + t];
    mth[t] = a;
  }
  __syncthreads();
  if (t < 64) {
    float a = ipb[128 + t];
    for (int k = 0; k < 64; k++) a += mth[k] * ipw[(128 + t) * 64 + k];
    vv[t] = a;
  }
  __syncthreads();
  if (t < 64) {
    float a = outb[t];
    for (int k = 0; k < 64; k++) a += vv[k] * outw[t * 64 + k];
    ov[t] = a;
  }
  __syncthreads();
  if (t < 192) {
    float af = bihf[t], ar = bihr[t];
    for (int k = 0; k < 64; k++) {
      af += ov[k] * wihf[t * 130 + k];
      ar += ov[k] * wihr[t * 130 + k];
    }
    ws[WS_GICF + t] = af;
    ws[WS_GICR + t] = ar;
  }
}

// ---------------------------------------------------------------- kernel B1
// grid 1024, block 256 (4 waves), 64 rows/block.
// LDS: ctile 50176 + cxout 9216 + iw 2560 + pes 1280 + pis 256 + sacc 16
//    = 63504 B (< 64 KB) -> 2 blocks/CU.
__global__ __launch_bounds__(256) void kB1(
    const float* __restrict__ theta, const float* __restrict__ context,
    const float* __restrict__ ctxw, const float* __restrict__ ctxb,
    const float* __restrict__ idealw, const float* __restrict__ idealb,
    const float* __restrict__ pe, const float* __restrict__ pi,
    const float* __restrict__ fw, const float* __restrict__ fb,
    float* __restrict__ dout, float* __restrict__ ws)
{
  __shared__ __align__(16) _Float16 ctile[64 * 392];  // context fp16, stride 392
  __shared__ __align__(16) _Float16 cxout[64 * 72];   // ctx result fp16
  __shared__ float iw[NP * 128];
  __shared__ float pes[NP * 64];
  __shared__ float pis[64];
  __shared__ float sacc[4];
  int t = threadIdx.x, lane = t & 63, wv = t >> 6;
  int q = lane >> 4, c = lane & 15;
  int Rbase = blockIdx.x << 6;

  // ---- stage context 64x384 fp32 -> fp16 LDS (coalesced float4) ----
  {
    const float4* src = (const float4*)(context + (size_t)Rbase * CTXD);
    for (int idx = t; idx < 6144; idx += 256) {
      int row = idx / 96, pos = idx - row * 96;
      *(h4*)&ctile[row * 392 + pos * 4] = cvt4(src[idx]);
    }
  }
  // ---- B-fragments (ctx_w rows) straight from global into 12 h8 regs ----
  h8 bf[12];
  {
    const float* wp = ctxw + (wv * 16 + c) * CTXD + q * 8;
#pragma unroll
    for (int ks = 0; ks < 12; ks++) {
      float4 u0 = *(const float4*)(wp + ks * 32);
      float4 u1 = *(const float4*)(wp + ks * 32 + 4);
      h8 b = {(_Float16)u0.x, (_Float16)u0.y, (_Float16)u0.z, (_Float16)u0.w,
              (_Float16)u1.x, (_Float16)u1.y, (_Float16)u1.z, (_Float16)u1.w};
      bf[ks] = b;
    }
  }
  for (int idx = t; idx < NP * 128; idx += 256) iw[idx] = idealw[idx];
  for (int idx = t; idx < NP * 64; idx += 256) pes[idx] = pe[idx];
  if (t < 64) pis[t] = pi[t];
  float cbv = ctxb[lane];
  float fwv = fw[0], fbv = fb[0];
  float ibv[NP];
#pragma unroll
  for (int l = 0; l < NP; l++) ibv[l] = idealb[l];
  __syncthreads();

  // ---- MFMA: wave wv computes cols [16wv,16wv+16) for all 64 rows ----
#pragma unroll
  for (int mt = 0; mt < 4; mt++) {
    const _Float16* ar = &ctile[(mt * 16 + c) * 392 + q * 8];
    f32x4 acc = (f32x4)(0.f);
#pragma unroll
    for (int ks = 0; ks < 12; ks++) {
      h8 av = *(const h8*)(ar + ks * 32);
      acc = __builtin_amdgcn_mfma_f32_16x16x32_f16(av, bf[ks], acc, 0, 0, 0);
    }
#pragma unroll
    for (int reg = 0; reg < 4; reg++)
      cxout[(mt * 16 + q * 4 + reg) * 72 + wv * 16 + c] = (_Float16)acc[reg];
  }
  __syncthreads();

  // ---- per-row epilogue: wave wv handles rows 4i+wv ----
  float wacc = 0.f;
  for (int i = 0; i < 16; i++) {
    int lr = (i << 2) + wv;
    int row = Rbase + lr;
    float th = theta[(row << 6) + lane];
    float cx = (float)cxout[lr * 72 + lane] + cbv;

    float L[NP];
#pragma unroll
    for (int l = 0; l < NP; l++) {
      float p = th * iw[l * 128 + lane] + cx * iw[l * 128 + 64 + lane];
      L[l] = wsum(p) + ibv[l];
    }
    float mx = L[0];
#pragma unroll
    for (int l = 1; l < NP; l++) mx = fmaxf(mx, L[l]);
    float P[NP], s = 0.f;
#pragma unroll
    for (int l = 0; l < NP; l++) { P[l] = __expf(L[l] - mx); s += P[l]; }
    float inv = 1.f / s;
#pragma unroll
    for (int l = 0; l < NP; l++) P[l] *= inv;
    if (lane < NP) {
      float v = P[0];
      if (lane == 1) v = P[1];
      else if (lane == 2) v = P[2];
      else if (lane == 3) v = P[3];
      else if (lane == 4) v = P[4];
      dout[O5 + row * NP + lane] = v;
    }

    float ti = 0.f;
#pragma unroll
    for (int l = 0; l < NP; l++) ti += P[l] * pes[l * 64 + lane];

    float a0 = th * th, a1 = ti * ti, a2 = th * ti;
    float dd = ti - pis[lane];
    float a3 = dd * dd;
#pragma unroll
    for (int m = 1; m < 64; m <<= 1) {
      a0 += __shfl_xor(a0, m, 64);
      a1 += __shfl_xor(a1, m, 64);
      a2 += __shfl_xor(a2, m, 64);
      a3 += __shfl_xor(a3, m, 64);
    }
    wacc += a0 - 2.f * a2 + a1;

    if (lane == 0) {
      float na = sqrtf(a0), nb = sqrtf(a1);
      float qq = 1.f / ((na + EPSV) * (nb + EPSV));
      float num = a2 * qq;
      float den = fmaxf(na * nb * qq, EPSV);
      dout[O3 + row] = num / den;
      float fq = sqrtf(a3);
      float om = tanhf_(fq * fwv + fbv) * (1.f + 0.1f * __sinf(fq));
      dout[O4 + row] = om;
    }
  }
  if (lane == 0) sacc[wv] = wacc;
  __syncthreads();
  if (t == 0) ws[WS_PART + blockIdx.x] = sacc[0] + sacc[1] + sacc[2] + sacc[3];
}

// ---------------------------------------------------------------- kernel B2
// grid 1024, block 256 (4 waves), 64 rows/block. MFMA MLP 64->128->64.
// LDS: tth 9216 + w1h 18432 + mid 17408 + w2h 17408 + 768 = 63232 B.
__global__ __launch_bounds__(256) void kB2(
    const float* __restrict__ theta,
    const float* __restrict__ w1, const float* __restrict__ b1,
    const float* __restrict__ w2, const float* __restrict__ b2,
    float* __restrict__ dout)
{
  __shared__ __align__(16) _Float16 tth[64 * 72];    // theta fp16
  __shared__ __align__(16) _Float16 w1h[128 * 72];   // [n=128][k=64]
  __shared__ __align__(16) _Float16 mid[64 * 136];   // tanh acts [m][128]
  __shared__ __align__(16) _Float16 w2h[64 * 136];   // [n=64][k=128]
  __shared__ float b1s[128], b2s[64];
  int t = threadIdx.x, lane = t & 63, wv = t >> 6;
  int q = lane >> 4, c = lane & 15;
  int Rbase = blockIdx.x << 6;

  {
    const float4* src = (const float4*)(theta + (size_t)Rbase * 64);
    for (int idx = t; idx < 1024; idx += 256) {
      int row = idx >> 4, pos = idx & 15;
      *(h4*)&tth[row * 72 + pos * 4] = cvt4(src[idx]);
    }
    const float4* s1 = (const float4*)w1;
    for (int idx = t; idx < 2048; idx += 256) {
      int n = idx >> 4, pos = idx & 15;
      *(h4*)&w1h[n * 72 + pos * 4] = cvt4(s1[idx]);
    }
    const float4* s2 = (const float4*)w2;
    for (int idx = t; idx < 2048; idx += 256) {
      int n = idx >> 5, pos = idx & 31;
      *(h4*)&w2h[n * 136 + pos * 4] = cvt4(s2[idx]);
    }
  }
  if (t < 128) b1s[t] = b1[t];
  if (t < 64) b2s[t] = b2[t];
  __syncthreads();

  // ---- layer 1: wave wv owns rows [16wv,16wv+16) ----
  const _Float16* ar = &tth[(wv * 16 + c) * 72 + q * 8];
  h8 a0 = *(const h8*)(ar);
  h8 a1 = *(const h8*)(ar + 32);
#pragma unroll
  for (int tn = 0; tn < 8; tn++) {
    const _Float16* br = &w1h[(tn * 16 + c) * 72 + q * 8];
    f32x4 acc = (f32x4)(0.f);
    acc = __builtin_amdgcn_mfma_f32_16x16x32_f16(a0, *(const h8*)(br),      acc, 0, 0, 0);
    acc = __builtin_amdgcn_mfma_f32_16x16x32_f16(a1, *(const h8*)(br + 32), acc, 0, 0, 0);
    float bv = b1s[tn * 16 + c];
#pragma unroll
    for (int reg = 0; reg < 4; reg++)
      mid[(wv * 16 + q * 4 + reg) * 136 + tn * 16 + c] = (_Float16)tanhf_(acc[reg] + bv);
  }
  __syncthreads();

  // ---- layer 2 ----
  const _Float16* am = &mid[(wv * 16 + c) * 136 + q * 8];
  h8 m0 = *(const h8*)(am);
  h8 m1 = *(const h8*)(am + 32);
  h8 m2 = *(const h8*)(am + 64);
  h8 m3 = *(const h8*)(am + 96);
#pragma unroll
  for (int tn = 0; tn < 4; tn++) {
    const _Float16* br = &w2h[(tn * 16 + c) * 136 + q * 8];
    f32x4 acc = (f32x4)(0.f);
    acc = __builtin_amdgcn_mfma_f32_16x16x32_f16(m0, *(const h8*)(br),      acc, 0, 0, 0);
    acc = __builtin_amdgcn_mfma_f32_16x16x32_f16(m1, *(const h8*)(br + 32), acc, 0, 0, 0);
    acc = __builtin_amdgcn_mfma_f32_16x16x32_f16(m2, *(const h8*)(br + 64), acc, 0, 0, 0);
    acc = __builtin_amdgcn_mfma_f32_16x16x32_f16(m3, *(const h8*)(br + 96), acc, 0, 0, 0);
    float bv = b2s[tn * 16 + c];
#pragma unroll
    for (int reg = 0; reg < 4; reg++) {
      int row = Rbase + wv * 16 + q * 4 + reg;
      dout[O2 + (row << 6) + tn * 16 + c] = fmaxf(acc[reg] + bv, 0.f);
    }
  }
}

// ---------------------------------------------------------------- kernel S
__global__ __launch_bounds__(256) void kS(float* __restrict__ ws)
{
  __shared__ double sd[256];
  int t = threadIdx.x;
  double a = 0.0;
  for (int i = t; i < NPART; i += 256) a += (double)ws[WS_PART + i];
  sd[t] = a;
  __syncthreads();
  for (int off = 128; off > 0; off >>= 1) {
    if (t < off) sd[t] += sd[t + off];
    __syncthreads();
  }
  if (t == 0) ws[WS_STRESS] = (float)sd[0];
}

// ---------------------------------------------------------------- kernel E
__global__ __launch_bounds__(256) void kE(float* __restrict__ dout,
                                          const float* __restrict__ ws)
{
  float sc = 0.001f * ws[WS_STRESS];
  int i = blockIdx.x * 256 + threadIdx.x;
  float4* p = (float4*)(dout + O2);
  float4 v = p[i];
  v.x += sc; v.y += sc; v.z += sc; v.w += sc;
  p[i] = v;
}

// ---------------------------------------------------------------- kernel C
// MFMA bi-GRU. grid (256, 2): bx covers 256 rows (4 M-blocks of 64), by=dir.
__global__ __launch_bounds__(256) void kC(
    const float* __restrict__ theta, const float* __restrict__ hprev,
    const float* __restrict__ wihf, const float* __restrict__ whhf,
    const float* __restrict__ bhhf,
    const float* __restrict__ wihr, const float* __restrict__ whhr,
    const float* __restrict__ bhhr,
    const float* __restrict__ ws, float* __restrict__ dout)
{
  __shared__ __align__(16) _Float16 WRZ[128 * 136];  // r,z gates: k=[e_c(64)|h(64)]
  __shared__ __align__(16) _Float16 WN [64 * 72];    // i_n gate: k=e_c only
  __shared__ __align__(16) _Float16 WHN[64 * 72];    // h_n gate: k=h only
  __shared__ __align__(16) _Float16 ABuf[64 * 136];  // [row][e_c(64)|h(64)] fp16
  __shared__ float cg[192], wes[192], wre[192], wom[192], bhn[64];
  __shared__ float sLDS[64], rLDS[64], oLDS[64];

  int t = threadIdx.x, lane = t & 63, wv = t >> 6;
  int q = lane >> 4, col = lane & 15;
  int dir = blockIdx.y;
  const float* WIH = dir ? wihr : wihf;
  const float* WHH = dir ? whhr : whhf;
  const float* BHH = dir ? bhhr : bhhf;
  const float* GIC = ws + (dir ? WS_GICR : WS_GICF);

  for (int idx = t; idx < 128 * 128; idx += 256) {
    int n = idx >> 7, k = idx & 127;
    float v = (k < 64) ? WIH[n * 130 + 64 + k] : WHH[n * 64 + (k - 64)];
    WRZ[n * 136 + k] = (_Float16)v;
  }
  for (int idx = t; idx < 64 * 64; idx += 256) {
    int n = idx >> 6, k = idx & 63;
    WN [n * 72 + k] = (_Float16)WIH[(128 + n) * 130 + 64 + k];
    WHN[n * 72 + k] = (_Float16)WHH[(128 + n) * 64 + k];
  }
  if (t < 192) {
    float s = 0.f;
    for (int k = 0; k < 64; k++) s += WIH[t * 130 + 64 + k];
    wes[t] = s;
    wre[t] = WIH[t * 130 + 128];
    wom[t] = WIH[t * 130 + 129];
    cg[t]  = GIC[t] + (t < 128 ? BHH[t] : 0.f);
  }
  if (t < 64) bhn[t] = BHH[128 + t];
  __syncthreads();

  for (int m = 0; m < 4; m++) {
    int Mbase = (blockIdx.x << 8) + (m << 6);

    for (int i = 0; i < 16; i++) {
      int lr = (i << 2) + wv;
      int row = Mbase + lr;
      float ev = dout[O2 + (row << 6) + lane];
      float hv = hprev[dir * (BATCH * 64) + (row << 6) + lane];
      float sr = wsum(ev) * 0.015625f;
      ABuf[lr * 136 + lane]      = (_Float16)(ev - sr);
      ABuf[lr * 136 + 64 + lane] = (_Float16)hv;
      if (lane == 0) sLDS[lr] = sr;
    }
    if (t < 64) {
      rLDS[t] = dout[O3 + Mbase + t];
      oLDS[t] = dout[O4 + Mbase + t];
    }
    __syncthreads();

    const _Float16* arow = &ABuf[(16 * wv + col) * 136 + q * 8];
    h8 a0 = *(const h8*)(arow);
    h8 a1 = *(const h8*)(arow + 32);
    h8 a2 = *(const h8*)(arow + 64);
    h8 a3 = *(const h8*)(arow + 96);

    f32x4 accR[4], accZ[4], accN[4], accH[4];
#pragma unroll
    for (int td = 0; td < 4; td++) {
      accR[td] = (f32x4)(0.f); accZ[td] = (f32x4)(0.f);
      accN[td] = (f32x4)(0.f); accH[td] = (f32x4)(0.f);
    }
#pragma unroll
    for (int td = 0; td < 4; td++) {
      const _Float16* br = &WRZ[(td * 16 + col) * 136 + q * 8];
      accR[td] = __builtin_amdgcn_mfma_f32_16x16x32_f16(a0, *(const h8*)(br),      accR[td], 0, 0, 0);
      accR[td] = __builtin_amdgcn_mfma_f32_16x16x32_f16(a1, *(const h8*)(br + 32), accR[td], 0, 0, 0);
      accR[td] = __builtin_amdgcn_mfma_f32_16x16x32_f16(a2, *(const h8*)(br + 64), accR[td], 0, 0, 0);
      accR[td] = __builtin_amdgcn_mfma_f32_16x16x32_f16(a3, *(const h8*)(br + 96), accR[td], 0, 0, 0);
      const _Float16* bz = &WRZ[(64 + td * 16 + col) * 136 + q * 8];
      accZ[td] = __builtin_amdgcn_mfma_f32_16x16x32_f16(a0, *(const h8*)(bz),      accZ[td], 0, 0, 0);
      accZ[td] = __builtin_amdgcn_mfma_f32_16x16x32_f16(a1, *(const h8*)(bz + 32), accZ[td], 0, 0, 0);
      accZ[td] = __builtin_amdgcn_mfma_f32_16x16x32_f16(a2, *(const h8*)(bz + 64), accZ[td], 0, 0, 0);
      accZ[td] = __builtin_amdgcn_mfma_f32_16x16x32_f16(a3, *(const h8*)(bz + 96), accZ[td], 0, 0, 0);
      const _Float16* bn = &WN[(td * 16 + col) * 72 + q * 8];
      accN[td] = __builtin_amdgcn_mfma_f32_16x16x32_f16(a0, *(const h8*)(bn),      accN[td], 0, 0, 0);
      accN[td] = __builtin_amdgcn_mfma_f32_16x16x32_f16(a1, *(const h8*)(bn + 32), accN[td], 0, 0, 0);
      const _Float16* bh = &WHN[(td * 16 + col) * 72 + q * 8];
      accH[td] = __builtin_amdgcn_mfma_f32_16x16x32_f16(a2, *(const h8*)(bh),      accH[td], 0, 0, 0);
      accH[td] = __builtin_amdgcn_mfma_f32_16x16x32_f16(a3, *(const h8*)(bh + 32), accH[td], 0, 0, 0);
    }

#pragma unroll
    for (int reg = 0; reg < 4; reg++) {
      int lr  = 16 * wv + q * 4 + reg;
      int row = Mbase + lr;
      float sr = sLDS[lr], rv = rLDS[lr], ov = oLDS[lr];
#pragma unroll
      for (int td = 0; td < 4; td++) {
        int d = td * 16 + col;
        float hv = (float)ABuf[lr * 136 + 64 + d];
        float A0 = accR[td][reg] + cg[d]       + sr * wes[d]       + rv * wre[d]       + ov * wom[d];
        float A1 = accZ[td][reg] + cg[64 + d]  + sr * wes[64 + d]  + rv * wre[64 + d]  + ov * wom[64 + d];
        float AN = accN[td][reg] + cg[128 + d] + sr * wes[128 + d] + rv * wre[128 + d] + ov * wom[128 + d];
        float AH = accH[td][reg] + bhn[d];
        float r  = sigmoidf_(A0);
        float z  = sigmoidf_(A1);
        float nn = tanhf_(AN + r * AH);
        float hf = (1.f - z) * nn + z * hv;
        dout[O1 + dir * (BATCH * 64) + (row << 6) + d] = hf;
        if (dir == 0) {
          dout[(row << 6) + d] = 0.3f * theta[(row << 6) + d] + 0.7f * hf;
        }
      }
    }
    __syncthreads();
  }
}

// ---------------------------------------------------------------- launch
extern "C" void kernel_launch(void* const* d_in, const int* in_sizes, int n_in,
                              void* d_out, int out_size, void* d_ws, size_t ws_size,
                              hipStream_t stream)
{
  const float* theta   = (const float*)d_in[0];
  const float* context = (const float*)d_in[1];
  const float* h_prev  = (const float*)d_in[2];
  const float* memory  = (const float*)d_in[3];
  const float* tw      = (const float*)d_in[4];
  const float* ipw     = (const float*)d_in[5];
  const float* ipb     = (const float*)d_in[6];
  const float* outw    = (const float*)d_in[7];
  const float* outb    = (const float*)d_in[8];
  const float* ew1     = (const float*)d_in[9];
  const float* eb1     = (const float*)d_in[10];
  const float* ew2     = (const float*)d_in[11];
  const float* eb2     = (const float*)d_in[12];
  const float* pe      = (const float*)d_in[13];
  const float* cw      = (const float*)d_in[14];
  const float* cb      = (const float*)d_in[15];
  const float* iw      = (const float*)d_in[16];
  const float* ib      = (const float*)d_in[17];
  const float* wihf    = (const float*)d_in[18];
  const float* whhf    = (const float*)d_in[19];
  const float* bihf    = (const float*)d_in[20];
  const float* bhhf    = (const float*)d_in[21];
  const float* wihr    = (const float*)d_in[22];
  const float* whhr    = (const float*)d_in[23];
  const float* bihr    = (const float*)d_in[24];
  const float* bhhr    = (const float*)d_in[25];
  const float* fw      = (const float*)d_in[26];
  const float* fb      = (const float*)d_in[27];
  const float* pi      = (const float*)d_in[28];
  float* dout = (float*)d_out;
  float* ws   = (float*)d_ws;

  kA<<<1, 256, 0, stream>>>(memory, tw, ipw, ipb, outw, outb, wihf, bihf, wihr, bihr, ws);
  kB1<<<1024, 256, 0, stream>>>(theta, context, cw, cb, iw, ib, pe, pi, fw, fb, dout, ws);
  kB2<<<1024, 256, 0, stream>>>(theta, ew1, eb1, ew2, eb2, dout);
  kS<<<1, 256, 0, stream>>>(ws);
  kE<<<4096, 256, 0, stream>>>(dout, ws);
  kC<<<dim3(256, 2, 1), 256, 0, stream>>>(theta, h_prev, wihf, whhf, bhhf,
                                          wihr, whhr, bhhr, ws, dout);
}

// Round 4
// 410.183 us; speedup vs baseline: 1.8794x; 1.0672x over previous
//
#include <hip/hip_runtime.h>
#include <math.h>

// ---------------------------------------------------------------------------
// REFT_Psi: B=65536 rows, DIM=64. 5 kernels:
//  kA  : mem-attn -> o_vec -> per-gate GRU constants; G=pe@pe^T, v=pe@pi,
//        pisq (theta_ideal is never materialized -- all consumers are
//        quadratic forms of P!)
//  kB1 : fused: ctx GEMM (MFMA) -> logits+tpe GEMM (MFMA, split-fp16 theta)
//        -> a0 diag-MFMA -> per-thread softmax/quadratic-form epilogue
//        (ZERO shuffles) + emotion MLP (MFMA) -> e (raw) in out2 slot
//  kS  : reduce 1024 stress partials (fp64)
//  kE  : out2 += 0.001*stress -> e_theta
//  kC  : bi-GRU via MFMA (mean-centered e_theta, fp32 rank-1 epilogue)
// Key algebra: a1=||ti||^2 = P^T G P; ti.pi = P.v; a2=theta.ti = sum P_l tpe_l
// with tpe = theta@pe^T folded into the logits GEMM as extra N-columns;
// a3 = a1 - 2 ti.pi + pisq; stress row = a0 - 2 a2 + a1. All fp32-exact given P.
// ---------------------------------------------------------------------------

#define BATCH 65536
#define CTXD  384
#define NP    5
#define EPSV  1e-8f

typedef _Float16 h8 __attribute__((ext_vector_type(8)));
typedef _Float16 h4 __attribute__((ext_vector_type(4)));
typedef float f32x4 __attribute__((ext_vector_type(4)));

// output offsets (floats)
#define O0 0
#define O1 4194304
#define O2 12582912
#define O3 16777216
#define O4 16842752
#define O5 16908288

// workspace offsets (floats)
#define WS_STRESS 0
#define WS_PART   256
#define NPART     1024
#define WS_GICF   1536
#define WS_GICR   1792
#define WS_G      2048   // 25 floats: pe@pe^T
#define WS_V      2080   // 5 floats: pe@prev_ideal
#define WS_PISQ   2088   // 1 float

__device__ __forceinline__ float wsum(float v) {
#pragma unroll
  for (int m = 1; m < 64; m <<= 1) v += __shfl_xor(v, m, 64);
  return v;
}

__device__ __forceinline__ float sigmoidf_(float x) {
  return 1.f / (1.f + __expf(-x));
}
__device__ __forceinline__ float tanhf_(float x) {
  float e2 = __expf(-2.f * x);
  return 2.f / (1.f + e2) - 1.f;
}

__device__ __forceinline__ h4 cvt4(float4 v) {
  h4 o = {(_Float16)v.x, (_Float16)v.y, (_Float16)v.z, (_Float16)v.w};
  return o;
}

// ---------------------------------------------------------------- kernel A
__global__ __launch_bounds__(256) void kA(
    const float* __restrict__ memory, const float* __restrict__ tw,
    const float* __restrict__ ipw, const float* __restrict__ ipb,
    const float* __restrict__ outw, const float* __restrict__ outb,
    const float* __restrict__ wihf, const float* __restrict__ bihf,
    const float* __restrict__ wihr, const float* __restrict__ bihr,
    const float* __restrict__ pe, const float* __restrict__ pi,
    float* __restrict__ ws)
{
  __shared__ float attn[16], mth[64], vv[64], ov[64];
  int t = threadIdx.x;
  if (t == 0) {
    float m = tw[0];
#pragma unroll
    for (int i = 1; i < 10; i++) m = fmaxf(m, tw[i]);
    float e[10]; float s = 0.f;
#pragma unroll
    for (int i = 0; i < 10; i++) { e[i] = __expf(tw[i] - m); s += e[i]; }
#pragma unroll
    for (int i = 0; i < 10; i++) attn[i] = e[i] / s;
  }
  // quadratic-form constants
  if (t < 25) {
    int l = t / 5, m = t - l * 5;
    float s = 0.f;
    for (int d = 0; d < 64; d++) s += pe[l * 64 + d] * pe[m * 64 + d];
    ws[WS_G + t] = s;
  } else if (t >= 32 && t < 37) {
    int l = t - 32;
    float s = 0.f;
    for (int d = 0; d < 64; d++) s += pe[l * 64 + d] * pi[d];
    ws[WS_V + l] = s;
  } else if (t == 40) {
    float s = 0.f;
    for (int d = 0; d < 64; d++) s += pi[d] * pi[d];
    ws[WS_PISQ] = s;
  }
  __syncthreads();
  if (t < 64) {
    float a = 0.f;
#pragma unroll
    for (int m = 0; m < 10; m++) a += attn[m] * memory[m * 64 + t];
    mth[t] = a;
  }
  __syncthreads();
  if (t < 64) {
    float a = ipb[128 + t];
    for (int k = 0; k < 64; k++) a += mth[k] * ipw[(128 + t) * 64 + k];
    vv[t] = a;
  }
  __syncthreads();
  if (t < 64) {
    float a = outb[t];
    for (int k = 0; k < 64; k++) a += vv[k] * outw[t * 64 + k];
    ov[t] = a;
  }
  __syncthreads();
  if (t < 192) {
    float af = bihf[t], ar = bihr[t];
    for (int k = 0; k < 64; k++) {
      af += ov[k] * wihf[t * 130 + k];
      ar += ov[k] * wihr[t * 130 + k];
    }
    ws[WS_GICF + t] = af;
    ws[WS_GICR + t] = ar;
  }
}

// ---------------------------------------------------------------- kernel B1
// Fused ctx GEMM + logits/tpe + a0 + softmax/quadratic-forms + emotion MLP.
// grid 1024, block 256 (4 waves), 64 rows/block.
// LDS: R-region 50176 (aliased across phases) + cxout 9216 = 59392 B.
__global__ __launch_bounds__(256) void kB1(
    const float* __restrict__ theta, const float* __restrict__ context,
    const float* __restrict__ ctxw, const float* __restrict__ ctxb,
    const float* __restrict__ idealw, const float* __restrict__ idealb,
    const float* __restrict__ pe,
    const float* __restrict__ w1, const float* __restrict__ b1,
    const float* __restrict__ w2, const float* __restrict__ b2,
    const float* __restrict__ fw, const float* __restrict__ fb,
    float* __restrict__ dout, float* __restrict__ ws)
{
  __shared__ __align__(16) char R[50176];
  __shared__ __align__(16) _Float16 cxout[64 * 72];
  // phase 0/1 alias:
  _Float16* ctile = (_Float16*)R;                 // 64 x 392 halves
  // phase 2+ aliases:
  _Float16* tthhi = (_Float16*)R;                 //  9216: 64 x 72
  _Float16* tthlo = (_Float16*)(R + 9216);        //  9216: 64 x 72
  _Float16* mid   = (_Float16*)(R + 18432);       // 17408: 64 x 136
  float*    Lb    = (float*)(R + 35840);          //  4352: 64 x 17
  float*    a0b   = (float*)(R + 40192);          //   256
  float*    parts = (float*)(R + 40448);          //   256

  int t = threadIdx.x, lane = t & 63, wv = t >> 6;
  int q = lane >> 4, c = lane & 15;
  int Rbase = blockIdx.x << 6;

  // ---- P0: stage context 64x384 fp32 -> fp16 LDS ----
  {
    const float4* src = (const float4*)(context + (size_t)Rbase * CTXD);
    for (int idx = t; idx < 6144; idx += 256) {
      int row = idx / 96, pos = idx - row * 96;
      *(h4*)&ctile[row * 392 + pos * 4] = cvt4(src[idx]);
    }
  }
  // B-fragments for ctx GEMM (wave owns cols 16wv..16wv+16)
  h8 bf[12];
  {
    const float* wp = ctxw + (wv * 16 + c) * CTXD + q * 8;
#pragma unroll
    for (int ks = 0; ks < 12; ks++) {
      float4 u0 = *(const float4*)(wp + ks * 32);
      float4 u1 = *(const float4*)(wp + ks * 32 + 4);
      h8 b = {(_Float16)u0.x, (_Float16)u0.y, (_Float16)u0.z, (_Float16)u0.w,
              (_Float16)u1.x, (_Float16)u1.y, (_Float16)u1.z, (_Float16)u1.w};
      bf[ks] = b;
    }
  }
  float cbv = ctxb[wv * 16 + c];
  __syncthreads();

  // ---- P1: ctx GEMM -> cxout (fp16, bias folded in) ----
#pragma unroll
  for (int mt = 0; mt < 4; mt++) {
    const _Float16* ar = &ctile[(mt * 16 + c) * 392 + q * 8];
    f32x4 acc = (f32x4)(0.f);
#pragma unroll
    for (int ks = 0; ks < 12; ks++) {
      h8 av = *(const h8*)(ar + ks * 32);
      acc = __builtin_amdgcn_mfma_f32_16x16x32_f16(av, bf[ks], acc, 0, 0, 0);
    }
#pragma unroll
    for (int reg = 0; reg < 4; reg++)
      cxout[(mt * 16 + q * 4 + reg) * 72 + wv * 16 + c] = (_Float16)(acc[reg] + cbv);
  }
  __syncthreads();   // ctile dead; cxout complete

  // ---- P2: stage theta hi/lo (split fp16) ----
  {
    const float4* ts = (const float4*)(theta + (size_t)Rbase * 64);
    for (int idx = t; idx < 1024; idx += 256) {
      int row = idx >> 4, pos = idx & 15;
      float4 v = ts[idx];
      h4 hi = cvt4(v);
      float4 lo = {v.x - (float)hi[0], v.y - (float)hi[1],
                   v.z - (float)hi[2], v.w - (float)hi[3]};
      *(h4*)&tthhi[row * 72 + pos * 4] = hi;
      *(h4*)&tthlo[row * 72 + pos * 4] = cvt4(lo);
    }
  }
  // B-fragments for logits/tpe GEMM: rows 0-4 iw, 5-9 pe-hi, 10-14 pe-lo
  h8 bw[4];
#pragma unroll
  for (int ks = 0; ks < 4; ks++) {
#pragma unroll
    for (int j = 0; j < 8; j++) {
      int k = ks * 32 + q * 8 + j;
      float v = 0.f;
      if (c < 5) v = idealw[c * 128 + k];
      else if (c < 10) { if (k < 64) v = pe[(c - 5) * 64 + k]; }
      else if (c < 15) {
        if (k < 64) { float p = pe[(c - 10) * 64 + k]; v = p - (float)(_Float16)p; }
      }
      bw[ks][j] = (_Float16)v;
    }
  }
  __syncthreads();   // tth staged

  // ---- P3: wave wv owns rows [16wv,16wv+16) from here on ----
  const _Float16* ahp = &tthhi[(16 * wv + c) * 72 + q * 8];
  const _Float16* alp = &tthlo[(16 * wv + c) * 72 + q * 8];
  const _Float16* acp = &cxout[(16 * wv + c) * 72 + q * 8];
  h8 ah0 = *(const h8*)(ahp);
  h8 ah1 = *(const h8*)(ahp + 32);
  h8 al0 = *(const h8*)(alp);
  h8 al1 = *(const h8*)(alp + 32);
  h8 ac0 = *(const h8*)(acp);
  h8 ac1 = *(const h8*)(acp + 32);

  // logits + tpe (K = [theta(64) | cx(64)], lo-pass on theta half)
  f32x4 Lacc = (f32x4)(0.f);
  Lacc = __builtin_amdgcn_mfma_f32_16x16x32_f16(ah0, bw[0], Lacc, 0, 0, 0);
  Lacc = __builtin_amdgcn_mfma_f32_16x16x32_f16(ah1, bw[1], Lacc, 0, 0, 0);
  Lacc = __builtin_amdgcn_mfma_f32_16x16x32_f16(ac0, bw[2], Lacc, 0, 0, 0);
  Lacc = __builtin_amdgcn_mfma_f32_16x16x32_f16(ac1, bw[3], Lacc, 0, 0, 0);
  Lacc = __builtin_amdgcn_mfma_f32_16x16x32_f16(al0, bw[0], Lacc, 0, 0, 0);
  Lacc = __builtin_amdgcn_mfma_f32_16x16x32_f16(al1, bw[1], Lacc, 0, 0, 0);
#pragma unroll
  for (int reg = 0; reg < 4; reg++)
    Lb[(16 * wv + q * 4 + reg) * 17 + c] = Lacc[reg];

  // a0 = ||theta||^2 via diag: hi.hi + 2 hi.lo
  {
    f32x4 hh = (f32x4)(0.f), hl = (f32x4)(0.f);
    hh = __builtin_amdgcn_mfma_f32_16x16x32_f16(ah0, ah0, hh, 0, 0, 0);
    hh = __builtin_amdgcn_mfma_f32_16x16x32_f16(ah1, ah1, hh, 0, 0, 0);
    hl = __builtin_amdgcn_mfma_f32_16x16x32_f16(ah0, al0, hl, 0, 0, 0);
    hl = __builtin_amdgcn_mfma_f32_16x16x32_f16(ah1, al1, hl, 0, 0, 0);
    if ((lane >> 4) == ((lane & 15) >> 2)) {
      int j = lane & 15;
      a0b[16 * wv + j] = hh[j & 3] + 2.f * hl[j & 3];
    }
  }

  // ---- emotion MLP layer 1 (reuses ah0/ah1) ----
#pragma unroll
  for (int tn = 0; tn < 8; tn++) {
    const float* wp = w1 + (tn * 16 + c) * 64 + q * 8;
    float4 u0 = *(const float4*)(wp);
    float4 u1 = *(const float4*)(wp + 4);
    float4 u2 = *(const float4*)(wp + 32);
    float4 u3 = *(const float4*)(wp + 36);
    h8 b0 = {(_Float16)u0.x, (_Float16)u0.y, (_Float16)u0.z, (_Float16)u0.w,
             (_Float16)u1.x, (_Float16)u1.y, (_Float16)u1.z, (_Float16)u1.w};
    h8 b1f = {(_Float16)u2.x, (_Float16)u2.y, (_Float16)u2.z, (_Float16)u2.w,
              (_Float16)u3.x, (_Float16)u3.y, (_Float16)u3.z, (_Float16)u3.w};
    f32x4 acc = (f32x4)(0.f);
    acc = __builtin_amdgcn_mfma_f32_16x16x32_f16(ah0, b0, acc, 0, 0, 0);
    acc = __builtin_amdgcn_mfma_f32_16x16x32_f16(ah1, b1f, acc, 0, 0, 0);
    float bv = b1[tn * 16 + c];
#pragma unroll
    for (int reg = 0; reg < 4; reg++)
      mid[(16 * wv + q * 4 + reg) * 136 + tn * 16 + c] = (_Float16)tanhf_(acc[reg] + bv);
  }

  // ---- MLP layer 2 (wave-local mid) ----
  {
    const _Float16* am = &mid[(16 * wv + c) * 136 + q * 8];
    h8 m0 = *(const h8*)(am);
    h8 m1 = *(const h8*)(am + 32);
    h8 m2 = *(const h8*)(am + 64);
    h8 m3 = *(const h8*)(am + 96);
#pragma unroll
    for (int tn = 0; tn < 4; tn++) {
      const float* wp = w2 + (tn * 16 + c) * 128 + q * 8;
      f32x4 acc = (f32x4)(0.f);
#pragma unroll
      for (int ks = 0; ks < 4; ks++) {
        float4 u0 = *(const float4*)(wp + ks * 32);
        float4 u1 = *(const float4*)(wp + ks * 32 + 4);
        h8 b = {(_Float16)u0.x, (_Float16)u0.y, (_Float16)u0.z, (_Float16)u0.w,
                (_Float16)u1.x, (_Float16)u1.y, (_Float16)u1.z, (_Float16)u1.w};
        h8 a = (ks == 0) ? m0 : (ks == 1) ? m1 : (ks == 2) ? m2 : m3;
        acc = __builtin_amdgcn_mfma_f32_16x16x32_f16(a, b, acc, 0, 0, 0);
      }
      float bv = b2[tn * 16 + c];
#pragma unroll
      for (int reg = 0; reg < 4; reg++) {
        int row = Rbase + 16 * wv + q * 4 + reg;
        dout[O2 + (row << 6) + tn * 16 + c] = fmaxf(acc[reg] + bv, 0.f);  // raw e
      }
    }
  }

  // ---- P4: per-row epilogue (wave-local: lanes 0-15 own rows 16wv+lane) ----
  if (lane < 16) {
    int r = 16 * wv + lane;
    int row = Rbase + r;
    float L[NP], tpe[NP];
#pragma unroll
    for (int l = 0; l < NP; l++) {
      L[l]   = Lb[r * 17 + l] + idealb[l];
      tpe[l] = Lb[r * 17 + 5 + l] + Lb[r * 17 + 10 + l];
    }
    float mx = L[0];
#pragma unroll
    for (int l = 1; l < NP; l++) mx = fmaxf(mx, L[l]);
    float P[NP], s = 0.f;
#pragma unroll
    for (int l = 0; l < NP; l++) { P[l] = __expf(L[l] - mx); s += P[l]; }
    float inv = 1.f / s;
#pragma unroll
    for (int l = 0; l < NP; l++) P[l] *= inv;
#pragma unroll
    for (int l = 0; l < NP; l++) dout[O5 + row * NP + l] = P[l];

    float a2 = 0.f, tipi = 0.f;
#pragma unroll
    for (int l = 0; l < NP; l++) {
      a2   += P[l] * tpe[l];
      tipi += P[l] * ws[WS_V + l];
    }
    float a1 = 0.f;
#pragma unroll
    for (int l = 0; l < NP; l++) {
      float pl = P[l];
#pragma unroll
      for (int m = 0; m < NP; m++) a1 += pl * P[m] * ws[WS_G + l * 5 + m];
    }
    float a0 = a0b[r];
    float a3 = fmaxf(a1 - 2.f * tipi + ws[WS_PISQ], 0.f);

    float na = sqrtf(a0), nb = sqrtf(a1);
    float qq = 1.f / ((na + EPSV) * (nb + EPSV));
    float num = a2 * qq;
    float den = fmaxf(na * nb * qq, EPSV);
    dout[O3 + row] = num / den;
    float fq = sqrtf(a3);
    float om = tanhf_(fq * fw[0] + fb[0]) * (1.f + 0.1f * __sinf(fq));
    dout[O4 + row] = om;

    parts[r] = a0 - 2.f * a2 + a1;
  }
  __syncthreads();
  if (t == 0) {
    float s = 0.f;
    for (int r = 0; r < 64; r++) s += parts[r];
    ws[WS_PART + blockIdx.x] = s;
  }
}

// ---------------------------------------------------------------- kernel S
__global__ __launch_bounds__(256) void kS(float* __restrict__ ws)
{
  __shared__ double sd[256];
  int t = threadIdx.x;
  double a = 0.0;
  for (int i = t; i < NPART; i += 256) a += (double)ws[WS_PART + i];
  sd[t] = a;
  __syncthreads();
  for (int off = 128; off > 0; off >>= 1) {
    if (t < off) sd[t] += sd[t + off];
    __syncthreads();
  }
  if (t == 0) ws[WS_STRESS] = (float)sd[0];
}

// ---------------------------------------------------------------- kernel E
__global__ __launch_bounds__(256) void kE(float* __restrict__ dout,
                                          const float* __restrict__ ws)
{
  float sc = 0.001f * ws[WS_STRESS];
  int i = blockIdx.x * 256 + threadIdx.x;
  float4* p = (float4*)(dout + O2);
  float4 v = p[i];
  v.x += sc; v.y += sc; v.z += sc; v.w += sc;
  p[i] = v;
}

// ---------------------------------------------------------------- kernel C
// MFMA bi-GRU. grid (256, 2): bx covers 256 rows (4 M-blocks of 64), by=dir.
__global__ __launch_bounds__(256) void kC(
    const float* __restrict__ theta, const float* __restrict__ hprev,
    const float* __restrict__ wihf, const float* __restrict__ whhf,
    const float* __restrict__ bhhf,
    const float* __restrict__ wihr, const float* __restrict__ whhr,
    const float* __restrict__ bhhr,
    const float* __restrict__ ws, float* __restrict__ dout)
{
  __shared__ __align__(16) _Float16 WRZ[128 * 136];
  __shared__ __align__(16) _Float16 WN [64 * 72];
  __shared__ __align__(16) _Float16 WHN[64 * 72];
  __shared__ __align__(16) _Float16 ABuf[64 * 136];
  __shared__ float cg[192], wes[192], wre[192], wom[192], bhn[64];
  __shared__ float sLDS[64], rLDS[64], oLDS[64];

  int t = threadIdx.x, lane = t & 63, wv = t >> 6;
  int q = lane >> 4, col = lane & 15;
  int dir = blockIdx.y;
  const float* WIH = dir ? wihr : wihf;
  const float* WHH = dir ? whhr : whhf;
  const float* BHH = dir ? bhhr : bhhf;
  const float* GIC = ws + (dir ? WS_GICR : WS_GICF);

  for (int idx = t; idx < 128 * 128; idx += 256) {
    int n = idx >> 7, k = idx & 127;
    float v = (k < 64) ? WIH[n * 130 + 64 + k] : WHH[n * 64 + (k - 64)];
    WRZ[n * 136 + k] = (_Float16)v;
  }
  for (int idx = t; idx < 64 * 64; idx += 256) {
    int n = idx >> 6, k = idx & 63;
    WN [n * 72 + k] = (_Float16)WIH[(128 + n) * 130 + 64 + k];
    WHN[n * 72 + k] = (_Float16)WHH[(128 + n) * 64 + k];
  }
  if (t < 192) {
    float s = 0.f;
    for (int k = 0; k < 64; k++) s += WIH[t * 130 + 64 + k];
    wes[t] = s;
    wre[t] = WIH[t * 130 + 128];
    wom[t] = WIH[t * 130 + 129];
    cg[t]  = GIC[t] + (t < 128 ? BHH[t] : 0.f);
  }
  if (t < 64) bhn[t] = BHH[128 + t];
  __syncthreads();

  for (int m = 0; m < 4; m++) {
    int Mbase = (blockIdx.x << 8) + (m << 6);

    for (int i = 0; i < 16; i++) {
      int lr = (i << 2) + wv;
      int row = Mbase + lr;
      float ev = dout[O2 + (row << 6) + lane];
      float hv = hprev[dir * (BATCH * 64) + (row << 6) + lane];
      float sr = wsum(ev) * 0.015625f;
      ABuf[lr * 136 + lane]      = (_Float16)(ev - sr);
      ABuf[lr * 136 + 64 + lane] = (_Float16)hv;
      if (lane == 0) sLDS[lr] = sr;
    }
    if (t < 64) {
      rLDS[t] = dout[O3 + Mbase + t];
      oLDS[t] = dout[O4 + Mbase + t];
    }
    __syncthreads();

    const _Float16* arow = &ABuf[(16 * wv + col) * 136 + q * 8];
    h8 a0 = *(const h8*)(arow);
    h8 a1 = *(const h8*)(arow + 32);
    h8 a2 = *(const h8*)(arow + 64);
    h8 a3 = *(const h8*)(arow + 96);

    f32x4 accR[4], accZ[4], accN[4], accH[4];
#pragma unroll
    for (int td = 0; td < 4; td++) {
      accR[td] = (f32x4)(0.f); accZ[td] = (f32x4)(0.f);
      accN[td] = (f32x4)(0.f); accH[td] = (f32x4)(0.f);
    }
#pragma unroll
    for (int td = 0; td < 4; td++) {
      const _Float16* br = &WRZ[(td * 16 + col) * 136 + q * 8];
      accR[td] = __builtin_amdgcn_mfma_f32_16x16x32_f16(a0, *(const h8*)(br),      accR[td], 0, 0, 0);
      accR[td] = __builtin_amdgcn_mfma_f32_16x16x32_f16(a1, *(const h8*)(br + 32), accR[td], 0, 0, 0);
      accR[td] = __builtin_amdgcn_mfma_f32_16x16x32_f16(a2, *(const h8*)(br + 64), accR[td], 0, 0, 0);
      accR[td] = __builtin_amdgcn_mfma_f32_16x16x32_f16(a3, *(const h8*)(br + 96), accR[td], 0, 0, 0);
      const _Float16* bz = &WRZ[(64 + td * 16 + col) * 136 + q * 8];
      accZ[td] = __builtin_amdgcn_mfma_f32_16x16x32_f16(a0, *(const h8*)(bz),      accZ[td], 0, 0, 0);
      accZ[td] = __builtin_amdgcn_mfma_f32_16x16x32_f16(a1, *(const h8*)(bz + 32), accZ[td], 0, 0, 0);
      accZ[td] = __builtin_amdgcn_mfma_f32_16x16x32_f16(a2, *(const h8*)(bz + 64), accZ[td], 0, 0, 0);
      accZ[td] = __builtin_amdgcn_mfma_f32_16x16x32_f16(a3, *(const h8*)(bz + 96), accZ[td], 0, 0, 0);
      const _Float16* bn = &WN[(td * 16 + col) * 72 + q * 8];
      accN[td] = __builtin_amdgcn_mfma_f32_16x16x32_f16(a0, *(const h8*)(bn),      accN[td], 0, 0, 0);
      accN[td] = __builtin_amdgcn_mfma_f32_16x16x32_f16(a1, *(const h8*)(bn + 32), accN[td], 0, 0, 0);
      const _Float16* bh = &WHN[(td * 16 + col) * 72 + q * 8];
      accH[td] = __builtin_amdgcn_mfma_f32_16x16x32_f16(a2, *(const h8*)(bh),      accH[td], 0, 0, 0);
      accH[td] = __builtin_amdgcn_mfma_f32_16x16x32_f16(a3, *(const h8*)(bh + 32), accH[td], 0, 0, 0);
    }

#pragma unroll
    for (int reg = 0; reg < 4; reg++) {
      int lr  = 16 * wv + q * 4 + reg;
      int row = Mbase + lr;
      float sr = sLDS[lr], rv = rLDS[lr], ov = oLDS[lr];
#pragma unroll
      for (int td = 0; td < 4; td++) {
        int d = td * 16 + col;
        float hv = (float)ABuf[lr * 136 + 64 + d];
        float A0 = accR[td][reg] + cg[d]       + sr * wes[d]       + rv * wre[d]       + ov * wom[d];
        float A1 = accZ[td][reg] + cg[64 + d]  + sr * wes[64 + d]  + rv * wre[64 + d]  + ov * wom[64 + d];
        float AN = accN[td][reg] + cg[128 + d] + sr * wes[128 + d] + rv * wre[128 + d] + ov * wom[128 + d];
        float AH = accH[td][reg] + bhn[d];
        float r  = sigmoidf_(A0);
        float z  = sigmoidf_(A1);
        float nn = tanhf_(AN + r * AH);
        float hf = (1.f - z) * nn + z * hv;
        dout[O1 + dir * (BATCH * 64) + (row << 6) + d] = hf;
        if (dir == 0) {
          dout[(row << 6) + d] = 0.3f * theta[(row << 6) + d] + 0.7f * hf;
        }
      }
    }
    __syncthreads();
  }
}

// ---------------------------------------------------------------- launch
extern "C" void kernel_launch(void* const* d_in, const int* in_sizes, int n_in,
                              void* d_out, int out_size, void* d_ws, size_t ws_size,
                              hipStream_t stream)
{
  const float* theta   = (const float*)d_in[0];
  const float* context = (const float*)d_in[1];
  const float* h_prev  = (const float*)d_in[2];
  const float* memory  = (const float*)d_in[3];
  const float* tw      = (const float*)d_in[4];
  const float* ipw     = (const float*)d_in[5];
  const float* ipb     = (const float*)d_in[6];
  const float* outw    = (const float*)d_in[7];
  const float* outb    = (const float*)d_in[8];
  const float* ew1     = (const float*)d_in[9];
  const float* eb1     = (const float*)d_in[10];
  const float* ew2     = (const float*)d_in[11];
  const float* eb2     = (const float*)d_in[12];
  const float* pe      = (const float*)d_in[13];
  const float* cw      = (const float*)d_in[14];
  const float* cb      = (const float*)d_in[15];
  const float* iw      = (const float*)d_in[16];
  const float* ib      = (const float*)d_in[17];
  const float* wihf    = (const float*)d_in[18];
  const float* whhf    = (const float*)d_in[19];
  const float* bihf    = (const float*)d_in[20];
  const float* bhhf    = (const float*)d_in[21];
  const float* wihr    = (const float*)d_in[22];
  const float* whhr    = (const float*)d_in[23];
  const float* bihr    = (const float*)d_in[24];
  const float* bhhr    = (const float*)d_in[25];
  const float* fw      = (const float*)d_in[26];
  const float* fb      = (const float*)d_in[27];
  const float* pi      = (const float*)d_in[28];
  float* dout = (float*)d_out;
  float* ws   = (float*)d_ws;

  kA<<<1, 256, 0, stream>>>(memory, tw, ipw, ipb, outw, outb, wihf, bihf,
                            wihr, bihr, pe, pi, ws);
  kB1<<<1024, 256, 0, stream>>>(theta, context, cw, cb, iw, ib, pe,
                                ew1, eb1, ew2, eb2, fw, fb, dout, ws);
  kS<<<1, 256, 0, stream>>>(ws);
  kE<<<4096, 256, 0, stream>>>(dout, ws);
  kC<<<dim3(256, 2, 1), 256, 0, stream>>>(theta, h_prev, wihf, whhf, bhhf,
                                          wihr, whhr, bhhr, ws, dout);
}